// Round 20
// baseline (149.306 us; speedup 1.0000x reference)
//
#include <hip/hip_runtime.h>
#include <hip/hip_bf16.h>

#define NSP   1568      // L*H*W (spatial tokens)
#define SEQ   1569      // 1 + NSP
#define CDIM  768
#define NHEAD 12
#define NTOT  6276      // B * SEQ
#define BATCH 4
#define NBH   48        // BATCH * NHEAD
#define SPADQ 1664      // padded packed q rows (26 * 64 = 13 * 128)
#define SPADK 1664      // padded packed keys  (13 * 128)
// PACKED ORDER: s' = spatial index for s' in [0,1568), cls at s'=1568,
// zeros in [1569,1664). Softmax is k-permutation-invariant; attn epilogue
// maps q'->seq row (q'==1568 -> 0, else q'+1).

typedef __bf16 bf16x8 __attribute__((ext_vector_type(8)));
typedef float  f32x4  __attribute__((ext_vector_type(4)));

static __device__ __forceinline__ unsigned pkbf(float a, float b) {
    __hip_bfloat16 ha = __float2bfloat16(a), hb = __float2bfloat16(b);
    return (unsigned)*(unsigned short*)&ha | ((unsigned)*(unsigned short*)&hb << 16);
}

// ---------------------------------------------------------------------------
// Fused prepass (one launch): z=0 Q, z=1 K, z=2 V.  (W handled by proj.)
// Q/K: [d][sp] fp32 -> [bh][s'][d] bf16 via LDS transpose (Q pre-scaled by
// HD^-0.5*log2e).  V: -> [bh][d][s'] bf16.
// Tiles 0..23 interior: aligned float4 loads / vector stores.
// Tiles 24 (spatial tail + cls) and 25 (zeros) take the scalar path.
// ---------------------------------------------------------------------------
__global__ __launch_bounds__(256) void pack_all(
    const float* __restrict__ qg, const float* __restrict__ kg,
    const float* __restrict__ vg, const float* __restrict__ cq,
    const float* __restrict__ ck, const float* __restrict__ cv,
    __hip_bfloat16* __restrict__ Qb, __hip_bfloat16* __restrict__ Kb,
    __hip_bfloat16* __restrict__ Vb)
{
    const int t  = threadIdx.x;
    const int z  = blockIdx.z;
    const int st = blockIdx.x;          // 64-row s'-tile (0..25)
    const int bh = blockIdx.y;
    const int b = bh / NHEAD, h = bh % NHEAD;

    if (z == 2) {                       // V pack (no transpose)
        const float* g = vg + ((size_t)b * CDIM + h * 64) * NSP;
        const float* c = cv + b * CDIM + h * 64;
        if (st < 24) {                  // interior: aligned float4 copy
            const int s0 = st * 64 + (t & 15) * 4;
            const int dr = t >> 4;
            #pragma unroll
            for (int i = 0; i < 4; ++i) {
                const int d = dr + i * 16;
                const float4 v4 = *(const float4*)(g + (size_t)d * NSP + s0);
                __hip_bfloat16 hv[4] = {
                    __float2bfloat16(v4.x), __float2bfloat16(v4.y),
                    __float2bfloat16(v4.z), __float2bfloat16(v4.w)};
                *(uint2*)(Vb + ((size_t)bh * 64 + d) * SPADK + s0) = *(const uint2*)hv;
            }
        } else {                        // tail: spatial remainder + cls + zeros
            const int s = st * 64 + (t & 63);
            for (int i = 0; i < 16; ++i) {
                const int d = (t >> 6) * 16 + i;
                float v = 0.f;
                if (s < NSP)       v = g[(size_t)d * NSP + s];
                else if (s == NSP) v = c[d];
                Vb[((size_t)bh * 64 + d) * SPADK + s] = __float2bfloat16(v);
            }
        }
        return;
    }

    // z = 0/1: Q/K transpose-pack
    __shared__ float tile[64 * 68];     // stride 68 floats -> rows 16B-aligned
    const float* g = (z ? kg : qg) + ((size_t)b * CDIM + h * 64) * NSP;
    const float* c = (z ? ck : cq) + b * CDIM + h * 64;
    const float scale = z ? 1.f : 0.125f * 1.44269504f;

    if (st < 24) {                      // interior: aligned float4 loads
        const int sq = (t & 15) * 4;
        const int s0 = st * 64 + sq;
        const int dr = t >> 4;
        #pragma unroll
        for (int i = 0; i < 4; ++i) {
            const int d = dr + i * 16;
            float4 v4 = *(const float4*)(g + (size_t)d * NSP + s0);
            v4.x *= scale; v4.y *= scale; v4.z *= scale; v4.w *= scale;
            *(float4*)(&tile[d * 68 + sq]) = v4;
        }
    } else {                            // tail tiles
        const int sl = t & 63, s = st * 64 + sl;
        for (int i = 0; i < 16; ++i) {
            const int d = (t >> 6) * 16 + i;
            float v = 0.f;
            if (s < NSP)       v = g[(size_t)d * NSP + s];
            else if (s == NSP) v = c[d];
            tile[d * 68 + sl] = v * scale;
        }
    }
    __syncthreads();
    __hip_bfloat16* out = z ? Kb : Qb;
    const size_t rowbase = (size_t)bh * (z ? SPADK : SPADQ) + st * 64;
    const int dg = (t & 7) * 8;
    #pragma unroll
    for (int half = 0; half < 2; ++half) {
        const int r = (t >> 3) + half * 32;
        __hip_bfloat16 hv[8];
        #pragma unroll
        for (int j = 0; j < 8; ++j)
            hv[j] = __float2bfloat16(tile[(dg + j) * 68 + r]);
        *(uint4*)(out + (rowbase + r) * 64 + dg) = *(const uint4*)hv;
    }
}

// ---------------------------------------------------------------------------
// MFMA flash attention — r19 attn (measured 92.6 us) with DEAD-TAIL SKIP:
// chunk 12's second subtile (keys 1600..1663) is 100% masked (SEQ=1569),
// so its 20 MFMAs + 32 exp2 + P/V traffic contribute exactly zero — skip
// it (bit-identical output, -1/26 of per-wave work). Also guard the final
// iteration's redundant prefetch + staging store.
// XCD-grouped 1D grid, setprio clusters, 13 chunk-barriers (K dbuf 2x16KB),
// 4 waves x 32 q, V direct B-frags (vf0 pre-QK, vf1 post-pack), wave-
// private P, swapped-QK^T, no-rescale exp2 softmax, ones-column row sums.
// ---------------------------------------------------------------------------
__global__ __launch_bounds__(256, 3) void attn_mfma(
    const __hip_bfloat16* __restrict__ Qbp, const __hip_bfloat16* __restrict__ Kbp,
    const __hip_bfloat16* __restrict__ Vbp, __hip_bfloat16* __restrict__ xb)
{
    __shared__ char smem[49152];
    char* const Ksb0 = smem;            // [128 k][64 d] bf16 swizzled, chunk buf 0
    char* const Ksb1 = smem + 16384;    // chunk buf 1

    const int t    = threadIdx.x;
    const int lane = t & 63;
    const int w    = t >> 6;
    const int lo   = lane & 15, hi = lane >> 4;

    // ---- XCD-grouped decode: gid&7 = XCD (round-robin dispatch), each XCD
    //      owns 6 whole bh (slot/13) x 13 q-tiles (slot%13). Bijective: 624=8*78.
    const int gid  = blockIdx.x;
    const int slot = gid >> 3;
    const int bh   = (gid & 7) + 8 * (slot / 13);
    const int qb   = (slot % 13) * 128;
    const int b    = bh / NHEAD, h = bh % NHEAD;

    const unsigned short* Qg = (const unsigned short*)Qbp + ((size_t)bh * SPADQ + qb) * 64;
    const unsigned short* Kg = (const unsigned short*)Kbp + (size_t)bh * SPADK * 64;
    const unsigned short* Vg = (const unsigned short*)Vbp + (size_t)bh * 64 * SPADK;

    char* const Pw = smem + 32768 + w * 4096;   // per-wave [32 q][64 k] bf16 swz

    // ---- Q fragments in registers, once
    bf16x8 qf[2][2];
    #pragma unroll
    for (int qn = 0; qn < 2; ++qn)
        #pragma unroll
        for (int ks = 0; ks < 2; ++ks)
            qf[qn][ks] = *(const bf16x8*)(Qg + (w * 32 + qn * 16 + lo) * 64 + (ks * 4 + hi) * 8);

    f32x4 o[2][4];          // O accumulators: row q=hi*4+r, col d=dn*16+lo
    f32x4 l5[2];            // row-sum accumulators
    #pragma unroll
    for (int m = 0; m < 2; ++m) {
        l5[m] = (f32x4){0.f, 0.f, 0.f, 0.f};
        #pragma unroll
        for (int n = 0; n < 4; ++n) o[m][n] = (f32x4){0.f, 0.f, 0.f, 0.f};
    }

    bf16x8 ones;
    #pragma unroll
    for (int i = 0; i < 8; ++i) ones[i] = (__bf16)1.0f;

    // ---- K staging indices: 128 rows x 64 cols = 1024 x 16B chunks,
    //      256 threads x 4 chunks (rows sr + 32p, col sc)
    const int sr = t >> 3, sc = t & 7;   // sr in [0,32)

    // ---- prologue: chunk 0 -> Ksb0
    uint4 kreg[4];
    #pragma unroll
    for (int p = 0; p < 4; ++p)
        kreg[p] = *(const uint4*)(Kg + (size_t)(sr + 32 * p) * 64 + sc * 8);
    #pragma unroll
    for (int p = 0; p < 4; ++p) {
        const int r = sr + 32 * p;
        *(uint4*)(Ksb0 + r * 128 + ((sc ^ (r & 7)) * 16)) = kreg[p];
    }

    int cur = 0;

    for (int it = 0; it < 13; ++it) {
        __syncthreads();                        // chunk[cur] staged for all waves
        char* const Kcur = cur ? Ksb1 : Ksb0;
        char* const Knxt = cur ? Ksb0 : Ksb1;

        // prefetch next 128-key chunk into regs (skip on last iter)
        if (it < 12) {
            #pragma unroll
            for (int p = 0; p < 4; ++p)
                kreg[p] = *(const uint4*)(Kg + (size_t)((it + 1) * 128 + sr + 32 * p) * 64 + sc * 8);
        }

        // ---- two 64-key subtiles from the staged chunk
        #pragma unroll
        for (int sub = 0; sub < 2; ++sub) {
            if (it == 12 && sub == 1) continue; // keys 1600..1663 fully masked: zero contribution
            const int kb = it * 128 + sub * 64;
            char* const Ksub = Kcur + sub * 8192;

            // V fragments ks=0 (direct global, B-frag)
            uint4 vf0[4];
            #pragma unroll
            for (int dn = 0; dn < 4; ++dn)
                vf0[dn] = *(const uint4*)(Vg + (size_t)(dn * 16 + lo) * SPADK + kb + hi * 8);

            // ---- S^T = K Q^T  (prio-boosted MFMA cluster)
            f32x4 s[4][2];
            #pragma unroll
            for (int km = 0; km < 4; ++km)
                #pragma unroll
                for (int qn = 0; qn < 2; ++qn) s[km][qn] = (f32x4){0.f, 0.f, 0.f, 0.f};
            __builtin_amdgcn_s_setprio(1);
            #pragma unroll
            for (int ks = 0; ks < 2; ++ks) {
                bf16x8 ak[4];
                #pragma unroll
                for (int km = 0; km < 4; ++km)
                    ak[km] = *(const bf16x8*)(Ksub + (km * 16 + lo) * 128 + (((ks * 4 + hi) ^ (lo & 7)) * 16));
                #pragma unroll
                for (int km = 0; km < 4; ++km)
                    #pragma unroll
                    for (int qn = 0; qn < 2; ++qn)
                        s[km][qn] = __builtin_amdgcn_mfma_f32_16x16x32_bf16(ak[km], qf[qn][ks], s[km][qn], 0, 0, 0);
            }
            __builtin_amdgcn_s_setprio(0);

            if (it == 12) {                     // live subtile 0: mask keys 1569..1599
                #pragma unroll
                for (int km = 0; km < 4; ++km)
                    #pragma unroll
                    for (int r = 0; r < 4; ++r)
                        if (kb + km * 16 + hi * 4 + r >= SEQ) {
                            s[km][0][r] = -1e30f;
                            s[km][1][r] = -1e30f;
                        }
            }

            // ---- P = exp2(S); packed b64 writes into Pw[q][k] (swizzled)
            #pragma unroll
            for (int qn = 0; qn < 2; ++qn)
                #pragma unroll
                for (int km = 0; km < 4; ++km) {
                    const float p0 = exp2f(s[km][qn][0]);
                    const float p1 = exp2f(s[km][qn][1]);
                    const float p2 = exp2f(s[km][qn][2]);
                    const float p3 = exp2f(s[km][qn][3]);
                    uint2 pk;
                    pk.x = pkbf(p0, p1);
                    pk.y = pkbf(p2, p3);
                    const int row = qn * 16 + lo;
                    *(uint2*)(Pw + row * 128 + (((km * 2 + (hi >> 1)) ^ (lo & 7)) * 16) + (hi & 1) * 8) = pk;
                }

            // V fragments ks=1 (after packs — r17 schedule)
            uint4 vf1[4];
            #pragma unroll
            for (int dn = 0; dn < 4; ++dn)
                vf1[dn] = *(const uint4*)(Vg + (size_t)(dn * 16 + lo) * SPADK + kb + 32 + hi * 8);

            // ---- O += P V ; l += P * ones  (prio-boosted MFMA cluster)
            __builtin_amdgcn_s_setprio(1);
            #pragma unroll
            for (int ks = 0; ks < 2; ++ks) {
                bf16x8 ap[2];
                #pragma unroll
                for (int m = 0; m < 2; ++m)
                    ap[m] = *(const bf16x8*)(Pw + (m * 16 + lo) * 128 + (((ks * 4 + hi) ^ (lo & 7)) * 16));
                #pragma unroll
                for (int m = 0; m < 2; ++m) {
                    #pragma unroll
                    for (int dn = 0; dn < 4; ++dn) {
                        const bf16x8 bv = *(const bf16x8*)(ks ? &vf1[dn] : &vf0[dn]);
                        o[m][dn] = __builtin_amdgcn_mfma_f32_16x16x32_bf16(ap[m], bv, o[m][dn], 0, 0, 0);
                    }
                    l5[m] = __builtin_amdgcn_mfma_f32_16x16x32_bf16(ap[m], ones, l5[m], 0, 0, 0);
                }
            }
            __builtin_amdgcn_s_setprio(0);
        }

        // stage next chunk into the other buffer (skip on last iter)
        if (it < 12) {
            #pragma unroll
            for (int p = 0; p < 4; ++p) {
                const int r = sr + 32 * p;
                *(uint4*)(Knxt + r * 128 + ((sc ^ (r & 7)) * 16)) = kreg[p];
            }
        }
        cur ^= 1;
    }

    // ---- epilogue: normalize, store to xb[n][ci]; packed q' -> seq row
    #pragma unroll
    for (int m = 0; m < 2; ++m)
        #pragma unroll
        for (int r = 0; r < 4; ++r) {
            const float inv = 1.f / l5[m][r];
            const int qp = qb + w * 32 + m * 16 + hi * 4 + r;
            if (qp < SEQ) {
                const int sq = (qp == NSP) ? 0 : qp + 1;
                __hip_bfloat16* dst = xb + ((size_t)b * SEQ + sq) * CDIM + h * 64 + lo;
                #pragma unroll
                for (int dn = 0; dn < 4; ++dn)
                    dst[dn * 16] = __float2bfloat16(o[m][dn][r] * inv);
            }
        }
}

// ---------------------------------------------------------------------------
// MFMA projection, 128co x 64n tiles, XCD-GROUPED 1D GRID (600 slots, guard
// id>=594). W staged DIRECTLY FROM FP32 (cvt during LDS staging; W panels
// L2-local per XCD). x staging bf16 from attn.  (r18 version, validated.)
// ---------------------------------------------------------------------------
__global__ __launch_bounds__(256) void proj_mfma(
    const float* __restrict__ W, const __hip_bfloat16* __restrict__ xbp,
    const float* __restrict__ bias, float* __restrict__ xout,
    float* __restrict__ clsout)
{
    __shared__ char smem[24576];
    char* Ws = smem;            // [128 co][64 k] bf16, swizzled
    char* Xs = smem + 16384;    // [ 64 n][64 k] bf16, swizzled

    const int id = ((int)blockIdx.x & 7) * 75 + ((int)blockIdx.x >> 3);
    if (id >= 594) return;
    const int mb = (id / 99) * 128;
    const int nb = (id % 99) * 64;

    const int t    = threadIdx.x;
    const int lane = t & 63;
    const int w    = t >> 6;
    const int lo   = lane & 15, hi = lane >> 4;

    const float* Wg = W + (size_t)mb * CDIM;
    const unsigned short* Xg = (const unsigned short*)xbp + (size_t)nb * CDIM;

    f32x4 acc[4][2];
    #pragma unroll
    for (int m = 0; m < 4; ++m)
        #pragma unroll
        for (int n = 0; n < 2; ++n) acc[m][n] = (f32x4){0.f, 0.f, 0.f, 0.f};

    const bool xok[2] = { nb + ((t)       >> 3) < NTOT,
                          nb + ((t + 256) >> 3) < NTOT };
    float4 wreg[4][2];
    uint4 xreg[2];
    #pragma unroll
    for (int p = 0; p < 4; ++p) {
        const int ch = t + 256 * p;
        const float* src = Wg + (size_t)(ch >> 3) * CDIM + (ch & 7) * 8;
        wreg[p][0] = *(const float4*)src;
        wreg[p][1] = *(const float4*)(src + 4);
    }
    #pragma unroll
    for (int p = 0; p < 2; ++p) {
        const int ch = t + 256 * p;
        xreg[p] = xok[p] ? *(const uint4*)(Xg + (ch >> 3) * CDIM + (ch & 7) * 8)
                         : (uint4){0u, 0u, 0u, 0u};
    }

    for (int kt = 0; kt < 12; ++kt) {
        __syncthreads();
        #pragma unroll
        for (int p = 0; p < 4; ++p) {
            const int ch = t + 256 * p;
            const int r = ch >> 3, c = ch & 7;
            __hip_bfloat16 hv[8] = {
                __float2bfloat16(wreg[p][0].x), __float2bfloat16(wreg[p][0].y),
                __float2bfloat16(wreg[p][0].z), __float2bfloat16(wreg[p][0].w),
                __float2bfloat16(wreg[p][1].x), __float2bfloat16(wreg[p][1].y),
                __float2bfloat16(wreg[p][1].z), __float2bfloat16(wreg[p][1].w)};
            *(uint4*)(Ws + r * 128 + ((c ^ (r & 7)) * 16)) = *(const uint4*)hv;
        }
        #pragma unroll
        for (int p = 0; p < 2; ++p) {
            const int ch = t + 256 * p;
            const int r = ch >> 3, c = ch & 7;
            *(uint4*)(Xs + r * 128 + ((c ^ (r & 7)) * 16)) = xreg[p];
        }
        __syncthreads();
        if (kt + 1 < 12) {
            const int kb = (kt + 1) * 64;
            #pragma unroll
            for (int p = 0; p < 4; ++p) {
                const int ch = t + 256 * p;
                const float* src = Wg + (size_t)(ch >> 3) * CDIM + kb + (ch & 7) * 8;
                wreg[p][0] = *(const float4*)src;
                wreg[p][1] = *(const float4*)(src + 4);
            }
            #pragma unroll
            for (int p = 0; p < 2; ++p) {
                const int ch = t + 256 * p;
                xreg[p] = xok[p] ? *(const uint4*)(Xg + (ch >> 3) * CDIM + kb + (ch & 7) * 8)
                                 : (uint4){0u, 0u, 0u, 0u};
            }
        }
        #pragma unroll
        for (int ks = 0; ks < 2; ++ks) {
            bf16x8 aw[4], bx[2];
            #pragma unroll
            for (int m = 0; m < 4; ++m) {
                const int row = (w >> 1) * 64 + m * 16 + lo;
                aw[m] = *(const bf16x8*)(Ws + row * 128 + (((ks * 4 + hi) ^ (lo & 7)) * 16));
            }
            #pragma unroll
            for (int n = 0; n < 2; ++n) {
                const int row = (w & 1) * 32 + n * 16 + lo;
                bx[n] = *(const bf16x8*)(Xs + row * 128 + (((ks * 4 + hi) ^ (lo & 7)) * 16));
            }
            #pragma unroll
            for (int m = 0; m < 4; ++m)
                #pragma unroll
                for (int n = 0; n < 2; ++n)
                    acc[m][n] = __builtin_amdgcn_mfma_f32_16x16x32_bf16(aw[m], bx[n], acc[m][n], 0, 0, 0);
        }
    }

    // ---- epilogue: bias, scatter (s==0 -> cls, else spatial, co-major)
    const int cob = mb + (w >> 1) * 64;
    const int nbb = nb + (w & 1) * 32;
    #pragma unroll
    for (int m = 0; m < 4; ++m)
        #pragma unroll
        for (int r = 0; r < 4; ++r) {
            const int co = cob + m * 16 + hi * 4 + r;
            const float bv = bias[co];
            #pragma unroll
            for (int n4 = 0; n4 < 2; ++n4) {
                const int n = nbb + n4 * 16 + lo;
                if (n >= NTOT) continue;
                const int bq = n / SEQ;
                const int s  = n - bq * SEQ;
                const float val = acc[m][n4][r] + bv;
                if (s == 0) clsout[bq * CDIM + co] = val;
                else        xout[((size_t)bq * CDIM + co) * NSP + (s - 1)] = val;
            }
        }
}

extern "C" void kernel_launch(void* const* d_in, const int* in_sizes, int n_in,
                              void* d_out, int out_size, void* d_ws, size_t ws_size,
                              hipStream_t stream)
{
    const float* q  = (const float*)d_in[0];
    const float* k  = (const float*)d_in[1];
    const float* v  = (const float*)d_in[2];
    const float* cq = (const float*)d_in[3];
    const float* ck = (const float*)d_in[4];
    const float* cv = (const float*)d_in[5];
    const float* W  = (const float*)d_in[6];
    const float* bi = (const float*)d_in[7];

    float* out    = (float*)d_out;
    float* xout   = out;
    float* clsout = out + (size_t)BATCH * CDIM * NSP;

    __hip_bfloat16* Qb = (__hip_bfloat16*)d_ws;                 // 10.2 MB
    __hip_bfloat16* Kb = Qb + (size_t)NBH * SPADQ * 64;         // 10.2 MB
    __hip_bfloat16* Vb = Kb + (size_t)NBH * SPADK * 64;         // 10.2 MB
    __hip_bfloat16* xb = Vb + (size_t)NBH * 64 * SPADK;         //  9.6 MB

    pack_all <<<dim3(26, NBH, 3), 256, 0, stream>>>(q, k, v, cq, ck, cv,
                                                    Qb, Kb, Vb);
    attn_mfma<<<dim3(624),        256, 0, stream>>>(Qb, Kb, Vb, xb);
    proj_mfma<<<dim3(600),        256, 0, stream>>>(W, xb, bi, xout, clsout);
}

// Round 21
// 125.886 us; speedup vs baseline: 1.1860x; 1.1860x over previous
//
#include <hip/hip_runtime.h>
#include <hip/hip_bf16.h>

#define NSP   1568      // L*H*W (spatial tokens)
#define SEQ   1569      // 1 + NSP
#define CDIM  768
#define NHEAD 12
#define NTOT  6276      // B * SEQ
#define BATCH 4
#define NBH   48        // BATCH * NHEAD
#define SPADQ 1664      // padded packed q rows (26 * 64 = 13 * 128)
#define SPADK 1664      // padded packed keys  (13 * 128)
// PACKED ORDER: s' = spatial index for s' in [0,1568), cls at s'=1568,
// zeros in [1569,1664). Softmax is k-permutation-invariant; attn epilogue
// maps q'->seq row (q'==1568 -> 0, else q'+1).

typedef __bf16 bf16x8 __attribute__((ext_vector_type(8)));
typedef float  f32x4  __attribute__((ext_vector_type(4)));

static __device__ __forceinline__ unsigned pkbf(float a, float b) {
    __hip_bfloat16 ha = __float2bfloat16(a), hb = __float2bfloat16(b);
    return (unsigned)*(unsigned short*)&ha | ((unsigned)*(unsigned short*)&hb << 16);
}

// ---------------------------------------------------------------------------
// Fused prepass (one launch): z=0 Q, z=1 K, z=2 V.  (W handled by proj.)
// Q/K: [d][sp] fp32 -> [bh][s'][d] bf16 via LDS transpose (Q pre-scaled by
// HD^-0.5*log2e).  V: -> [bh][d][s'] bf16.
// Tiles 0..23 interior: aligned float4 loads / vector stores.
// Tiles 24 (spatial tail + cls) and 25 (zeros) take the scalar path.
// ---------------------------------------------------------------------------
__global__ __launch_bounds__(256) void pack_all(
    const float* __restrict__ qg, const float* __restrict__ kg,
    const float* __restrict__ vg, const float* __restrict__ cq,
    const float* __restrict__ ck, const float* __restrict__ cv,
    __hip_bfloat16* __restrict__ Qb, __hip_bfloat16* __restrict__ Kb,
    __hip_bfloat16* __restrict__ Vb)
{
    const int t  = threadIdx.x;
    const int z  = blockIdx.z;
    const int st = blockIdx.x;          // 64-row s'-tile (0..25)
    const int bh = blockIdx.y;
    const int b = bh / NHEAD, h = bh % NHEAD;

    if (z == 2) {                       // V pack (no transpose)
        const float* g = vg + ((size_t)b * CDIM + h * 64) * NSP;
        const float* c = cv + b * CDIM + h * 64;
        if (st < 24) {                  // interior: aligned float4 copy
            const int s0 = st * 64 + (t & 15) * 4;
            const int dr = t >> 4;
            #pragma unroll
            for (int i = 0; i < 4; ++i) {
                const int d = dr + i * 16;
                const float4 v4 = *(const float4*)(g + (size_t)d * NSP + s0);
                __hip_bfloat16 hv[4] = {
                    __float2bfloat16(v4.x), __float2bfloat16(v4.y),
                    __float2bfloat16(v4.z), __float2bfloat16(v4.w)};
                *(uint2*)(Vb + ((size_t)bh * 64 + d) * SPADK + s0) = *(const uint2*)hv;
            }
        } else {                        // tail: spatial remainder + cls + zeros
            const int s = st * 64 + (t & 63);
            for (int i = 0; i < 16; ++i) {
                const int d = (t >> 6) * 16 + i;
                float v = 0.f;
                if (s < NSP)       v = g[(size_t)d * NSP + s];
                else if (s == NSP) v = c[d];
                Vb[((size_t)bh * 64 + d) * SPADK + s] = __float2bfloat16(v);
            }
        }
        return;
    }

    // z = 0/1: Q/K transpose-pack
    __shared__ float tile[64 * 68];     // stride 68 floats -> rows 16B-aligned
    const float* g = (z ? kg : qg) + ((size_t)b * CDIM + h * 64) * NSP;
    const float* c = (z ? ck : cq) + b * CDIM + h * 64;
    const float scale = z ? 1.f : 0.125f * 1.44269504f;

    if (st < 24) {                      // interior: aligned float4 loads
        const int sq = (t & 15) * 4;
        const int s0 = st * 64 + sq;
        const int dr = t >> 4;
        #pragma unroll
        for (int i = 0; i < 4; ++i) {
            const int d = dr + i * 16;
            float4 v4 = *(const float4*)(g + (size_t)d * NSP + s0);
            v4.x *= scale; v4.y *= scale; v4.z *= scale; v4.w *= scale;
            *(float4*)(&tile[d * 68 + sq]) = v4;
        }
    } else {                            // tail tiles
        const int sl = t & 63, s = st * 64 + sl;
        for (int i = 0; i < 16; ++i) {
            const int d = (t >> 6) * 16 + i;
            float v = 0.f;
            if (s < NSP)       v = g[(size_t)d * NSP + s];
            else if (s == NSP) v = c[d];
            tile[d * 68 + sl] = v * scale;
        }
    }
    __syncthreads();
    __hip_bfloat16* out = z ? Kb : Qb;
    const size_t rowbase = (size_t)bh * (z ? SPADK : SPADQ) + st * 64;
    const int dg = (t & 7) * 8;
    #pragma unroll
    for (int half = 0; half < 2; ++half) {
        const int r = (t >> 3) + half * 32;
        __hip_bfloat16 hv[8];
        #pragma unroll
        for (int j = 0; j < 8; ++j)
            hv[j] = __float2bfloat16(tile[(dg + j) * 68 + r]);
        *(uint4*)(out + (rowbase + r) * 64 + dg) = *(const uint4*)hv;
    }
}

// ---------------------------------------------------------------------------
// MFMA flash attention — r17 attn VERBATIM (measured 92.6 us; every body
// perturbation tried — subtile pipelining, vf1 hoist, dead-tail skip —
// regressed 8-26 us by breaking the compiler's static schedule; this body
// is a validated local optimum and is left untouched).
// XCD-grouped 1D grid (K/V L2-local per XCD), setprio around MFMA clusters,
// 13 chunk-barriers (K dbuf 2x16KB), 4 waves x 32 q, V direct B-frags
// (vf0 pre-QK, vf1 post-pack), wave-private P, swapped-QK^T, no-rescale
// exp2 softmax, ones-column row sums.
// Epilogue maps packed q' -> seq row (q'==1568 -> 0, else q'+1).
// ---------------------------------------------------------------------------
__global__ __launch_bounds__(256, 3) void attn_mfma(
    const __hip_bfloat16* __restrict__ Qbp, const __hip_bfloat16* __restrict__ Kbp,
    const __hip_bfloat16* __restrict__ Vbp, __hip_bfloat16* __restrict__ xb)
{
    __shared__ char smem[49152];
    char* const Ksb0 = smem;            // [128 k][64 d] bf16 swizzled, chunk buf 0
    char* const Ksb1 = smem + 16384;    // chunk buf 1

    const int t    = threadIdx.x;
    const int lane = t & 63;
    const int w    = t >> 6;
    const int lo   = lane & 15, hi = lane >> 4;

    // ---- XCD-grouped decode: gid&7 = XCD (round-robin dispatch), each XCD
    //      owns 6 whole bh (slot/13) x 13 q-tiles (slot%13). Bijective: 624=8*78.
    const int gid  = blockIdx.x;
    const int slot = gid >> 3;
    const int bh   = (gid & 7) + 8 * (slot / 13);
    const int qb   = (slot % 13) * 128;
    const int b    = bh / NHEAD, h = bh % NHEAD;

    const unsigned short* Qg = (const unsigned short*)Qbp + ((size_t)bh * SPADQ + qb) * 64;
    const unsigned short* Kg = (const unsigned short*)Kbp + (size_t)bh * SPADK * 64;
    const unsigned short* Vg = (const unsigned short*)Vbp + (size_t)bh * 64 * SPADK;

    char* const Pw = smem + 32768 + w * 4096;   // per-wave [32 q][64 k] bf16 swz

    // ---- Q fragments in registers, once
    bf16x8 qf[2][2];
    #pragma unroll
    for (int qn = 0; qn < 2; ++qn)
        #pragma unroll
        for (int ks = 0; ks < 2; ++ks)
            qf[qn][ks] = *(const bf16x8*)(Qg + (w * 32 + qn * 16 + lo) * 64 + (ks * 4 + hi) * 8);

    f32x4 o[2][4];          // O accumulators: row q=hi*4+r, col d=dn*16+lo
    f32x4 l5[2];            // row-sum accumulators
    #pragma unroll
    for (int m = 0; m < 2; ++m) {
        l5[m] = (f32x4){0.f, 0.f, 0.f, 0.f};
        #pragma unroll
        for (int n = 0; n < 4; ++n) o[m][n] = (f32x4){0.f, 0.f, 0.f, 0.f};
    }

    bf16x8 ones;
    #pragma unroll
    for (int i = 0; i < 8; ++i) ones[i] = (__bf16)1.0f;

    // ---- K staging indices: 128 rows x 64 cols = 1024 x 16B chunks,
    //      256 threads x 4 chunks (rows sr + 32p, col sc)
    const int sr = t >> 3, sc = t & 7;   // sr in [0,32)

    // ---- prologue: chunk 0 -> Ksb0
    uint4 kreg[4];
    #pragma unroll
    for (int p = 0; p < 4; ++p)
        kreg[p] = *(const uint4*)(Kg + (size_t)(sr + 32 * p) * 64 + sc * 8);
    #pragma unroll
    for (int p = 0; p < 4; ++p) {
        const int r = sr + 32 * p;
        *(uint4*)(Ksb0 + r * 128 + ((sc ^ (r & 7)) * 16)) = kreg[p];
    }

    int cur = 0;

    for (int it = 0; it < 13; ++it) {
        __syncthreads();                        // chunk[cur] staged for all waves
        char* const Kcur = cur ? Ksb1 : Ksb0;
        char* const Knxt = cur ? Ksb0 : Ksb1;

        // prefetch next 128-key chunk into regs (clamped; last iter redundant)
        const int itn = (it + 1 < 13) ? it + 1 : it;
        #pragma unroll
        for (int p = 0; p < 4; ++p)
            kreg[p] = *(const uint4*)(Kg + (size_t)(itn * 128 + sr + 32 * p) * 64 + sc * 8);

        // ---- two 64-key subtiles from the staged chunk
        #pragma unroll
        for (int sub = 0; sub < 2; ++sub) {
            const int kb = it * 128 + sub * 64;
            char* const Ksub = Kcur + sub * 8192;

            // V fragments ks=0 (direct global, B-frag)
            uint4 vf0[4];
            #pragma unroll
            for (int dn = 0; dn < 4; ++dn)
                vf0[dn] = *(const uint4*)(Vg + (size_t)(dn * 16 + lo) * SPADK + kb + hi * 8);

            // ---- S^T = K Q^T  (prio-boosted MFMA cluster)
            f32x4 s[4][2];
            #pragma unroll
            for (int km = 0; km < 4; ++km)
                #pragma unroll
                for (int qn = 0; qn < 2; ++qn) s[km][qn] = (f32x4){0.f, 0.f, 0.f, 0.f};
            __builtin_amdgcn_s_setprio(1);
            #pragma unroll
            for (int ks = 0; ks < 2; ++ks) {
                bf16x8 ak[4];
                #pragma unroll
                for (int km = 0; km < 4; ++km)
                    ak[km] = *(const bf16x8*)(Ksub + (km * 16 + lo) * 128 + (((ks * 4 + hi) ^ (lo & 7)) * 16));
                #pragma unroll
                for (int km = 0; km < 4; ++km)
                    #pragma unroll
                    for (int qn = 0; qn < 2; ++qn)
                        s[km][qn] = __builtin_amdgcn_mfma_f32_16x16x32_bf16(ak[km], qf[qn][ks], s[km][qn], 0, 0, 0);
            }
            __builtin_amdgcn_s_setprio(0);

            if (it == 12) {                     // chunk 12: keys 1536..1663, mask k' >= SEQ
                #pragma unroll
                for (int km = 0; km < 4; ++km)
                    #pragma unroll
                    for (int r = 0; r < 4; ++r)
                        if (kb + km * 16 + hi * 4 + r >= SEQ) {
                            s[km][0][r] = -1e30f;
                            s[km][1][r] = -1e30f;
                        }
            }

            // ---- P = exp2(S); packed b64 writes into Pw[q][k] (swizzled)
            #pragma unroll
            for (int qn = 0; qn < 2; ++qn)
                #pragma unroll
                for (int km = 0; km < 4; ++km) {
                    const float p0 = exp2f(s[km][qn][0]);
                    const float p1 = exp2f(s[km][qn][1]);
                    const float p2 = exp2f(s[km][qn][2]);
                    const float p3 = exp2f(s[km][qn][3]);
                    uint2 pk;
                    pk.x = pkbf(p0, p1);
                    pk.y = pkbf(p2, p3);
                    const int row = qn * 16 + lo;
                    *(uint2*)(Pw + row * 128 + (((km * 2 + (hi >> 1)) ^ (lo & 7)) * 16) + (hi & 1) * 8) = pk;
                }

            // V fragments ks=1 (after packs — r17 schedule)
            uint4 vf1[4];
            #pragma unroll
            for (int dn = 0; dn < 4; ++dn)
                vf1[dn] = *(const uint4*)(Vg + (size_t)(dn * 16 + lo) * SPADK + kb + 32 + hi * 8);

            // ---- O += P V ; l += P * ones  (prio-boosted MFMA cluster)
            __builtin_amdgcn_s_setprio(1);
            #pragma unroll
            for (int ks = 0; ks < 2; ++ks) {
                bf16x8 ap[2];
                #pragma unroll
                for (int m = 0; m < 2; ++m)
                    ap[m] = *(const bf16x8*)(Pw + (m * 16 + lo) * 128 + (((ks * 4 + hi) ^ (lo & 7)) * 16));
                #pragma unroll
                for (int m = 0; m < 2; ++m) {
                    #pragma unroll
                    for (int dn = 0; dn < 4; ++dn) {
                        const bf16x8 bv = *(const bf16x8*)(ks ? &vf1[dn] : &vf0[dn]);
                        o[m][dn] = __builtin_amdgcn_mfma_f32_16x16x32_bf16(ap[m], bv, o[m][dn], 0, 0, 0);
                    }
                    l5[m] = __builtin_amdgcn_mfma_f32_16x16x32_bf16(ap[m], ones, l5[m], 0, 0, 0);
                }
            }
            __builtin_amdgcn_s_setprio(0);
        }

        // stage next chunk into the other buffer (visible after next barrier)
        #pragma unroll
        for (int p = 0; p < 4; ++p) {
            const int r = sr + 32 * p;
            *(uint4*)(Knxt + r * 128 + ((sc ^ (r & 7)) * 16)) = kreg[p];
        }
        cur ^= 1;
    }

    // ---- epilogue: normalize, store to xb[n][ci]; packed q' -> seq row
    #pragma unroll
    for (int m = 0; m < 2; ++m)
        #pragma unroll
        for (int r = 0; r < 4; ++r) {
            const float inv = 1.f / l5[m][r];
            const int qp = qb + w * 32 + m * 16 + hi * 4 + r;
            if (qp < SEQ) {
                const int sq = (qp == NSP) ? 0 : qp + 1;
                __hip_bfloat16* dst = xb + ((size_t)b * SEQ + sq) * CDIM + h * 64 + lo;
                #pragma unroll
                for (int dn = 0; dn < 4; ++dn)
                    dst[dn * 16] = __float2bfloat16(o[m][dn][r] * inv);
            }
        }
}

// ---------------------------------------------------------------------------
// MFMA projection, 128co x 64n tiles, XCD-GROUPED 1D GRID (600 slots, guard
// id>=594). W staged DIRECTLY FROM FP32 (cvt during LDS staging; W panels
// L2-local per XCD). x staging bf16 from attn.  (r18 version, validated.)
// ---------------------------------------------------------------------------
__global__ __launch_bounds__(256) void proj_mfma(
    const float* __restrict__ W, const __hip_bfloat16* __restrict__ xbp,
    const float* __restrict__ bias, float* __restrict__ xout,
    float* __restrict__ clsout)
{
    __shared__ char smem[24576];
    char* Ws = smem;            // [128 co][64 k] bf16, swizzled
    char* Xs = smem + 16384;    // [ 64 n][64 k] bf16, swizzled

    const int id = ((int)blockIdx.x & 7) * 75 + ((int)blockIdx.x >> 3);
    if (id >= 594) return;
    const int mb = (id / 99) * 128;
    const int nb = (id % 99) * 64;

    const int t    = threadIdx.x;
    const int lane = t & 63;
    const int w    = t >> 6;
    const int lo   = lane & 15, hi = lane >> 4;

    const float* Wg = W + (size_t)mb * CDIM;
    const unsigned short* Xg = (const unsigned short*)xbp + (size_t)nb * CDIM;

    f32x4 acc[4][2];
    #pragma unroll
    for (int m = 0; m < 4; ++m)
        #pragma unroll
        for (int n = 0; n < 2; ++n) acc[m][n] = (f32x4){0.f, 0.f, 0.f, 0.f};

    const bool xok[2] = { nb + ((t)       >> 3) < NTOT,
                          nb + ((t + 256) >> 3) < NTOT };
    float4 wreg[4][2];
    uint4 xreg[2];
    #pragma unroll
    for (int p = 0; p < 4; ++p) {
        const int ch = t + 256 * p;
        const float* src = Wg + (size_t)(ch >> 3) * CDIM + (ch & 7) * 8;
        wreg[p][0] = *(const float4*)src;
        wreg[p][1] = *(const float4*)(src + 4);
    }
    #pragma unroll
    for (int p = 0; p < 2; ++p) {
        const int ch = t + 256 * p;
        xreg[p] = xok[p] ? *(const uint4*)(Xg + (ch >> 3) * CDIM + (ch & 7) * 8)
                         : (uint4){0u, 0u, 0u, 0u};
    }

    for (int kt = 0; kt < 12; ++kt) {
        __syncthreads();
        #pragma unroll
        for (int p = 0; p < 4; ++p) {
            const int ch = t + 256 * p;
            const int r = ch >> 3, c = ch & 7;
            __hip_bfloat16 hv[8] = {
                __float2bfloat16(wreg[p][0].x), __float2bfloat16(wreg[p][0].y),
                __float2bfloat16(wreg[p][0].z), __float2bfloat16(wreg[p][0].w),
                __float2bfloat16(wreg[p][1].x), __float2bfloat16(wreg[p][1].y),
                __float2bfloat16(wreg[p][1].z), __float2bfloat16(wreg[p][1].w)};
            *(uint4*)(Ws + r * 128 + ((c ^ (r & 7)) * 16)) = *(const uint4*)hv;
        }
        #pragma unroll
        for (int p = 0; p < 2; ++p) {
            const int ch = t + 256 * p;
            const int r = ch >> 3, c = ch & 7;
            *(uint4*)(Xs + r * 128 + ((c ^ (r & 7)) * 16)) = xreg[p];
        }
        __syncthreads();
        if (kt + 1 < 12) {
            const int kb = (kt + 1) * 64;
            #pragma unroll
            for (int p = 0; p < 4; ++p) {
                const int ch = t + 256 * p;
                const float* src = Wg + (size_t)(ch >> 3) * CDIM + kb + (ch & 7) * 8;
                wreg[p][0] = *(const float4*)src;
                wreg[p][1] = *(const float4*)(src + 4);
            }
            #pragma unroll
            for (int p = 0; p < 2; ++p) {
                const int ch = t + 256 * p;
                xreg[p] = xok[p] ? *(const uint4*)(Xg + (ch >> 3) * CDIM + kb + (ch & 7) * 8)
                                 : (uint4){0u, 0u, 0u, 0u};
            }
        }
        #pragma unroll
        for (int ks = 0; ks < 2; ++ks) {
            bf16x8 aw[4], bx[2];
            #pragma unroll
            for (int m = 0; m < 4; ++m) {
                const int row = (w >> 1) * 64 + m * 16 + lo;
                aw[m] = *(const bf16x8*)(Ws + row * 128 + (((ks * 4 + hi) ^ (lo & 7)) * 16));
            }
            #pragma unroll
            for (int n = 0; n < 2; ++n) {
                const int row = (w & 1) * 32 + n * 16 + lo;
                bx[n] = *(const bf16x8*)(Xs + row * 128 + (((ks * 4 + hi) ^ (lo & 7)) * 16));
            }
            #pragma unroll
            for (int m = 0; m < 4; ++m)
                #pragma unroll
                for (int n = 0; n < 2; ++n)
                    acc[m][n] = __builtin_amdgcn_mfma_f32_16x16x32_bf16(aw[m], bx[n], acc[m][n], 0, 0, 0);
        }
    }

    // ---- epilogue: bias, scatter (s==0 -> cls, else spatial, co-major)
    const int cob = mb + (w >> 1) * 64;
    const int nbb = nb + (w & 1) * 32;
    #pragma unroll
    for (int m = 0; m < 4; ++m)
        #pragma unroll
        for (int r = 0; r < 4; ++r) {
            const int co = cob + m * 16 + hi * 4 + r;
            const float bv = bias[co];
            #pragma unroll
            for (int n4 = 0; n4 < 2; ++n4) {
                const int n = nbb + n4 * 16 + lo;
                if (n >= NTOT) continue;
                const int bq = n / SEQ;
                const int s  = n - bq * SEQ;
                const float val = acc[m][n4][r] + bv;
                if (s == 0) clsout[bq * CDIM + co] = val;
                else        xout[((size_t)bq * CDIM + co) * NSP + (s - 1)] = val;
            }
        }
}

extern "C" void kernel_launch(void* const* d_in, const int* in_sizes, int n_in,
                              void* d_out, int out_size, void* d_ws, size_t ws_size,
                              hipStream_t stream)
{
    const float* q  = (const float*)d_in[0];
    const float* k  = (const float*)d_in[1];
    const float* v  = (const float*)d_in[2];
    const float* cq = (const float*)d_in[3];
    const float* ck = (const float*)d_in[4];
    const float* cv = (const float*)d_in[5];
    const float* W  = (const float*)d_in[6];
    const float* bi = (const float*)d_in[7];

    float* out    = (float*)d_out;
    float* xout   = out;
    float* clsout = out + (size_t)BATCH * CDIM * NSP;

    __hip_bfloat16* Qb = (__hip_bfloat16*)d_ws;                 // 10.2 MB
    __hip_bfloat16* Kb = Qb + (size_t)NBH * SPADQ * 64;         // 10.2 MB
    __hip_bfloat16* Vb = Kb + (size_t)NBH * SPADK * 64;         // 10.2 MB
    __hip_bfloat16* xb = Vb + (size_t)NBH * 64 * SPADK;         //  9.6 MB

    pack_all <<<dim3(26, NBH, 3), 256, 0, stream>>>(q, k, v, cq, ck, cv,
                                                    Qb, Kb, Vb);
    attn_mfma<<<dim3(624),        256, 0, stream>>>(Qb, Kb, Vb, xb);
    proj_mfma<<<dim3(600),        256, 0, stream>>>(W, xb, bi, xout, clsout);
}